// Round 5
// baseline (37.336 us; speedup 1.0000x reference)
//
#include <hip/hip_runtime.h>

#define B_SZ 32
#define T_PH 512
#define H_DIM 256
#define N_EDGES 255
#define MAX_LEN 4096
#define EXP_BLOCKS 2048   // 8 per CU; 64 frames per block; 16 iters of 4 frames

typedef float f32x4 __attribute__((ext_vector_type(4)));

// ---------------- Kernel A: shfl-scan + bin bisects + packed-frame fill ----------
// One block (512 thr) per batch row. frames[b][t] = ph | pi<<9 | ei<<17 (or -1)
__global__ void prep_kernel(const int* __restrict__ dur,
                            const float* __restrict__ pt,
                            const float* __restrict__ et,
                            const float* __restrict__ pbins,
                            const float* __restrict__ ebins,
                            int* __restrict__ frames,
                            float* __restrict__ mel_out) {
    const int b = blockIdx.x;
    const int tid = threadIdx.x;
    const int wave = tid >> 6;
    const int lane = tid & 63;
    __shared__ int cs[T_PH];
    __shared__ int packv[T_PH];
    __shared__ int wsum[8];
    __shared__ float pb[N_EDGES];
    __shared__ float eb[N_EDGES];

    if (tid < N_EDGES) pb[tid] = pbins[tid];
    else if (tid >= 256 && tid < 256 + N_EDGES) eb[tid - 256] = ebins[tid - 256];

    const int d = dur[b * T_PH + tid];
    // wave-level inclusive scan
    int v = d;
#pragma unroll
    for (int off = 1; off < 64; off <<= 1) {
        int u = __shfl_up(v, off, 64);
        if (lane >= off) v += u;
    }
    if (lane == 63) wsum[wave] = v;
    __syncthreads();
    int woff = 0;
#pragma unroll
    for (int w = 0; w < 8; ++w) woff += (w < wave) ? wsum[w] : 0;
    v += woff;
    cs[tid] = v;

    // per-phoneme bin bisects (side='left'), bins in LDS
    const float pv = pt[b * T_PH + tid];
    const float ev = et[b * T_PH + tid];
    int lo = 0, hi = N_EDGES;
    while (lo < hi) { int m = (lo + hi) >> 1; if (pb[m] < pv) lo = m + 1; else hi = m; }
    const int pi = lo;
    lo = 0; hi = N_EDGES;
    while (lo < hi) { int m = (lo + hi) >> 1; if (eb[m] < ev) lo = m + 1; else hi = m; }
    const int ei = lo;
    packv[tid] = tid | (pi << 9) | (ei << 17);
    __syncthreads();

    const int mel = cs[T_PH - 1];

    // each thread resolves 8 consecutive frames: one LDS bisect + monotone walk
    const int t0 = tid * 8;
    int p = 0;
    if (t0 < mel) {
        int l = 0, h = T_PH;   // searchsorted(cs, t0, side='right')
        while (l < h) { int m = (l + h) >> 1; if (cs[m] > t0) h = m; else l = m + 1; }
        p = l;
    }
    int o[8];
#pragma unroll
    for (int j = 0; j < 8; ++j) {
        const int t = t0 + j;
        int vv = -1;
        if (t < mel) {
            while (cs[p] <= t) ++p;
            vv = packv[p];
        }
        o[j] = vv;
    }
    int4* fr = (int4*)(frames + (size_t)b * MAX_LEN);
    fr[tid * 2]     = make_int4(o[0], o[1], o[2], o[3]);
    fr[tid * 2 + 1] = make_int4(o[4], o[5], o[6], o[7]);

    if (tid == T_PH - 1) mel_out[b] = (float)mel;  // exact for < 2^24
}

// ---------------- Kernel B: persistent, branchless, XCD-chunked ----------------
// 2048 blocks x 256 thr. Block owns 64 consecutive frames (same batch row).
__global__ void expand_kernel(const float* __restrict__ x,
                              const float* __restrict__ pemb,
                              const float* __restrict__ eemb,
                              const int* __restrict__ frames,
                              float* __restrict__ out) {
    const int wave  = threadIdx.x >> 6;          // 0..3
    const int lane4 = threadIdx.x & 63;
    // bijective XCD-chunk swizzle: XCD k gets contiguous frames (4 batch rows)
    const int phys = blockIdx.x;
    const int vb   = (phys & 7) * (EXP_BLOCKS / 8) + (phys >> 3);
    const int fbase = vb * 64;                   // block's first frame
    const int b = fbase >> 12;                   // batch row (constant per block)
    const float* __restrict__ xb = x + (size_t)b * T_PH * H_DIM;

    // all 16 wave-uniform indices up front (independent loads, one latency)
    int pks[16];
#pragma unroll
    for (int i = 0; i < 16; ++i)
        pks[i] = frames[fbase + i * 4 + wave];

#pragma unroll
    for (int i = 0; i < 16; ++i) {
        const int k  = pks[i];
        const int kk = k >= 0 ? k : 0;           // invalid -> row 0 (L1-resident)
        const int ph = kk & 511;
        const int pi = (kk >> 9) & 255;
        const int ei = (kk >> 17) & 255;
        const f32x4 a = ((const f32x4*)(xb   + (size_t)ph * H_DIM))[lane4];
        const f32x4 p = ((const f32x4*)(pemb + (size_t)pi * H_DIM))[lane4];
        const f32x4 e = ((const f32x4*)(eemb + (size_t)ei * H_DIM))[lane4];
        f32x4 r = a + p + e;
        const f32x4 z = {0.f, 0.f, 0.f, 0.f};
        r = (k >= 0) ? r : z;                    // cndmask, no branch
        const int frame = fbase + i * 4 + wave;
        __builtin_nontemporal_store(r, (f32x4*)out + (size_t)frame * 64 + lane4);
    }
}

extern "C" void kernel_launch(void* const* d_in, const int* in_sizes, int n_in,
                              void* d_out, int out_size, void* d_ws, size_t ws_size,
                              hipStream_t stream) {
    const float* x     = (const float*)d_in[0];
    const float* pt    = (const float*)d_in[1];
    const float* et    = (const float*)d_in[2];
    const float* pbins = (const float*)d_in[3];
    const float* ebins = (const float*)d_in[4];
    const float* pemb  = (const float*)d_in[5];
    const float* eemb  = (const float*)d_in[6];
    const int*   dur   = (const int*)d_in[7];

    float* out = (float*)d_out;                            // 32*4096*256 f32
    float* mel_out = out + (size_t)B_SZ * MAX_LEN * H_DIM; // 32 f32 (tuple tail)

    int* frames = (int*)d_ws;                              // 512 KB packed indices

    prep_kernel<<<B_SZ, T_PH, 0, stream>>>(dur, pt, et, pbins, ebins,
                                           frames, mel_out);

    expand_kernel<<<EXP_BLOCKS, 256, 0, stream>>>(x, pemb, eemb, frames, out);
}

// Round 6
// 33.796 us; speedup vs baseline: 1.1048x; 1.1048x over previous
//
#include <hip/hip_runtime.h>

#define B_SZ 32
#define T_PH 512
#define H_DIM 256
#define N_EDGES 255
#define MAX_LEN 4096

typedef float f32x4 __attribute__((ext_vector_type(4)));

// ---------------- Kernel A: scan + bin bisects + coalesced packed-frame fill ----------
// (byte-identical to the round-3 version that measured 33.2 us)
__global__ void prep_kernel(const int* __restrict__ dur,
                            const float* __restrict__ pt,
                            const float* __restrict__ et,
                            const float* __restrict__ pbins,
                            const float* __restrict__ ebins,
                            int* __restrict__ frames,
                            float* __restrict__ mel_out) {
    const int b = blockIdx.x;
    const int tid = threadIdx.x;
    __shared__ int cs[T_PH];
    __shared__ int packv[T_PH];
    __shared__ float pb[N_EDGES];
    __shared__ float eb[N_EDGES];

    if (tid < N_EDGES) pb[tid] = pbins[tid];
    else if (tid >= 256 && tid < 256 + N_EDGES) eb[tid - 256] = ebins[tid - 256];

    const int d = dur[b * T_PH + tid];
    cs[tid] = d;
    __syncthreads();
#pragma unroll
    for (int off = 1; off < T_PH; off <<= 1) {
        int v = (tid >= off) ? cs[tid - off] : 0;
        __syncthreads();
        cs[tid] += v;
        __syncthreads();
    }

    const float pv = pt[b * T_PH + tid];
    const float ev = et[b * T_PH + tid];
    int lo = 0, hi = N_EDGES;
    while (lo < hi) { int m = (lo + hi) >> 1; if (pb[m] < pv) lo = m + 1; else hi = m; }
    const int pi = lo;
    lo = 0; hi = N_EDGES;
    while (lo < hi) { int m = (lo + hi) >> 1; if (eb[m] < ev) lo = m + 1; else hi = m; }
    const int ei = lo;
    packv[tid] = tid | (pi << 9) | (ei << 17);
    __syncthreads();

    const int mel = cs[T_PH - 1];

    const int t0 = tid * 8;
    int p = 0;
    if (t0 < mel) {
        int l = 0, h = T_PH;
        while (l < h) { int m = (l + h) >> 1; if (cs[m] > t0) h = m; else l = m + 1; }
        p = l;
    }
    int o[8];
#pragma unroll
    for (int j = 0; j < 8; ++j) {
        const int t = t0 + j;
        int v = -1;
        if (t < mel) {
            while (cs[p] <= t) ++p;
            v = packv[p];
        }
        o[j] = v;
    }
    int4* fr = (int4*)(frames + (size_t)b * MAX_LEN);
    fr[tid * 2]     = make_int4(o[0], o[1], o[2], o[3]);
    fr[tid * 2 + 1] = make_int4(o[4], o[5], o[6], o[7]);

    if (tid == T_PH - 1) mel_out[b] = (float)mel;  // exact for < 2^24
}

// ---------------- Kernel B: 2 consecutive frames per wave, int2 idx, 3-way uniform ----
// 8 frames/block, 16384 blocks. Monotone tail => cases: VV (overlap 6 gathers),
// VT (boundary, once per row), TT (pure zero stream).
__global__ void expand_kernel(const float* __restrict__ x,
                              const float* __restrict__ pemb,
                              const float* __restrict__ eemb,
                              const int* __restrict__ frames,
                              float* __restrict__ out) {
    const int wave  = threadIdx.x >> 6;
    const int lane4 = threadIdx.x & 63;
    const int f0 = blockIdx.x * 8 + wave * 2;    // two consecutive frames
    const int b  = f0 >> 12;

    const int2 pk2 = *(const int2*)(frames + f0); // single 8B idx load
    const int pk0 = pk2.x, pk1 = pk2.y;

    f32x4* o0 = (f32x4*)out + (size_t)f0 * 64 + lane4;
    const f32x4 z = {0.f, 0.f, 0.f, 0.f};
    const float* __restrict__ xb = x + (size_t)b * T_PH * H_DIM;

    if ((pk0 | pk1) >= 0) {
        // both valid: 6 independent gathers in flight together
        const int ph0 = pk0 & 511, pi0 = (pk0 >> 9) & 255, ei0 = (pk0 >> 17) & 255;
        const int ph1 = pk1 & 511, pi1 = (pk1 >> 9) & 255, ei1 = (pk1 >> 17) & 255;
        const f32x4 a0 = ((const f32x4*)(xb   + (size_t)ph0 * H_DIM))[lane4];
        const f32x4 p0 = ((const f32x4*)(pemb + (size_t)pi0 * H_DIM))[lane4];
        const f32x4 e0 = ((const f32x4*)(eemb + (size_t)ei0 * H_DIM))[lane4];
        const f32x4 a1 = ((const f32x4*)(xb   + (size_t)ph1 * H_DIM))[lane4];
        const f32x4 p1 = ((const f32x4*)(pemb + (size_t)pi1 * H_DIM))[lane4];
        const f32x4 e1 = ((const f32x4*)(eemb + (size_t)ei1 * H_DIM))[lane4];
        __builtin_nontemporal_store(a0 + p0 + e0, o0);
        __builtin_nontemporal_store(a1 + p1 + e1, o0 + 64);
    } else if (pk0 >= 0) {
        // boundary: frame0 valid, frame1 tail
        const int ph0 = pk0 & 511, pi0 = (pk0 >> 9) & 255, ei0 = (pk0 >> 17) & 255;
        const f32x4 a0 = ((const f32x4*)(xb   + (size_t)ph0 * H_DIM))[lane4];
        const f32x4 p0 = ((const f32x4*)(pemb + (size_t)pi0 * H_DIM))[lane4];
        const f32x4 e0 = ((const f32x4*)(eemb + (size_t)ei0 * H_DIM))[lane4];
        __builtin_nontemporal_store(a0 + p0 + e0, o0);
        __builtin_nontemporal_store(z, o0 + 64);
    } else {
        // pure tail: zero streaming, no loads
        __builtin_nontemporal_store(z, o0);
        __builtin_nontemporal_store(z, o0 + 64);
    }
}

extern "C" void kernel_launch(void* const* d_in, const int* in_sizes, int n_in,
                              void* d_out, int out_size, void* d_ws, size_t ws_size,
                              hipStream_t stream) {
    const float* x     = (const float*)d_in[0];
    const float* pt    = (const float*)d_in[1];
    const float* et    = (const float*)d_in[2];
    const float* pbins = (const float*)d_in[3];
    const float* ebins = (const float*)d_in[4];
    const float* pemb  = (const float*)d_in[5];
    const float* eemb  = (const float*)d_in[6];
    const int*   dur   = (const int*)d_in[7];

    float* out = (float*)d_out;                            // 32*4096*256 f32
    float* mel_out = out + (size_t)B_SZ * MAX_LEN * H_DIM; // 32 f32 (tuple tail)

    int* frames = (int*)d_ws;                              // 512 KB packed indices

    prep_kernel<<<B_SZ, T_PH, 0, stream>>>(dur, pt, et, pbins, ebins,
                                           frames, mel_out);

    const int nframes = B_SZ * MAX_LEN;                    // 131072
    expand_kernel<<<nframes / 8, 256, 0, stream>>>(x, pemb, eemb, frames, out);
}